// Round 2
// 549.842 us; speedup vs baseline: 1.6570x; 1.6570x over previous
//
#include <hip/hip_runtime.h>
#include <math.h>

// SpectralNorm: sigma = max(1, s_max(w2d)/2); w = w_bar/sigma; conv3x3 pad1 + bias.
// x: [32,32,256,256] f32, w_bar: [32,32,3,3] f32, bias: [32] f32, out same as x.
//
// Conv is reformulated as implicit GEMM on the bf16 matrix cores with a 3-term
// bf16 split (xhi*whi + xlo*whi + xhi*wlo) for fp32-equivalent accuracy.

typedef __attribute__((ext_vector_type(8))) __bf16 frag8;    // MFMA A/B operand (4 VGPR)
typedef __attribute__((ext_vector_type(16))) float f32x16;   // MFMA C/D (16 VGPR)
typedef __attribute__((ext_vector_type(8))) unsigned short u16x8;

__device__ __forceinline__ unsigned short bf16bits(float v) {
  __bf16 h = (__bf16)v;
  return __builtin_bit_cast(unsigned short, h);
}

// ---------------- prep: sigma via G = W W^T, squaring + power iter ----------------
// Output: bf16 hi/lo split of w_bar/sigma in [q][k][c] layout (q = 3*dy+dx).
__global__ __launch_bounds__(256) void sn_prep_kernel(
    const float* __restrict__ w_bar,      // [32][288] row-major (k major)
    unsigned short* __restrict__ w_out)   // [2][9][32][32]: hi plane then lo plane
{
  __shared__ __align__(16) float sw[9216];    // [k][t]
  __shared__ __align__(16) float swT[9216];   // [t][k]
  __shared__ float G0[1024];
  __shared__ float Gpp[2048];
  __shared__ float vvec[32];
  __shared__ float svec[32];
  __shared__ float scal[2];
  const int tid = threadIdx.x;

  for (int i = tid; i < 9216; i += 256) {
    float v = w_bar[i];
    sw[i] = v;
    int k = i / 288;
    int t = i - k * 288;
    swT[t * 32 + k] = v;
  }
  __syncthreads();

  for (int e = tid; e < 1024; e += 256) {
    int i = e >> 5, j = e & 31;
    const float* ri = &sw[i * 288];
    float s = 0.f;
    for (int t = 0; t < 288; t += 4) {
      float4 a = *(const float4*)(ri + t);
      s = fmaf(a.x, swT[(t + 0) * 32 + j], s);
      s = fmaf(a.y, swT[(t + 1) * 32 + j], s);
      s = fmaf(a.z, swT[(t + 2) * 32 + j], s);
      s = fmaf(a.w, swT[(t + 3) * 32 + j], s);
    }
    G0[e] = s;
  }

  const float* src = G0;
  for (int sq = 0; sq < 6; ++sq) {
    float* dst = &Gpp[(sq & 1) * 1024];
    __syncthreads();
    for (int e = tid; e < 1024; e += 256) {
      int i = e >> 5, j = e & 31;
      float s = 0.f;
#pragma unroll
      for (int t = 0; t < 32; ++t)
        s = fmaf(src[i * 32 + t], src[t * 32 + j], s);
      dst[e] = s;
    }
    __syncthreads();
    float s0 = dst[0];
    float inv = (s0 > 0.f) ? (1.f / s0) : 1.f;
    __syncthreads();
    for (int e = tid; e < 1024; e += 256) dst[e] *= inv;
    src = dst;
  }

  if (tid < 32) vvec[tid] = 1.f;
  __syncthreads();
  for (int it = 0; it < 4; ++it) {
    if (tid < 32) {
      float s = 0.f;
#pragma unroll
      for (int j = 0; j < 32; ++j) s = fmaf(src[tid * 32 + j], vvec[j], s);
      svec[tid] = s;
    }
    __syncthreads();
    if (tid == 0) {
      float n2 = 0.f;
      for (int j = 0; j < 32; ++j) n2 += svec[j] * svec[j];
      scal[0] = (n2 > 0.f) ? rsqrtf(n2) : 0.f;
    }
    __syncthreads();
    if (tid < 32) vvec[tid] = svec[tid] * scal[0];
    __syncthreads();
  }

  if (tid < 32) {
    float s = 0.f;
#pragma unroll
    for (int j = 0; j < 32; ++j) s = fmaf(G0[tid * 32 + j], vvec[j], s);
    svec[tid] = s * vvec[tid];
  }
  __syncthreads();
  if (tid == 0) {
    float lam = 0.f;
    for (int j = 0; j < 32; ++j) lam += svec[j];
    lam = fmaxf(lam, 0.f);
    float sigma = fmaxf(1.f, 0.5f * sqrtf(lam));
    scal[1] = 1.f / sigma;
  }
  __syncthreads();
  float inv_sigma = scal[1];
  // emit bf16 hi/lo in [q][k][c] layout (e = q*1024 + k*32 + c)
  for (int e = tid; e < 9216; e += 256) {
    int q = e >> 10;
    int rem = e & 1023;
    int k = rem >> 5;
    int c = rem & 31;
    float w = sw[k * 288 + c * 9 + q] * inv_sigma;
    __bf16 hb = (__bf16)w;
    float lo = w - (float)hb;
    w_out[e] = __builtin_bit_cast(unsigned short, hb);
    w_out[9216 + e] = bf16bits(lo);
  }
}

// ---------------- conv: implicit GEMM on v_mfma_f32_32x32x16_bf16 ----------------
// Block: 256 thr (4 waves), tile = 8 out-rows x 64 cols x 32 k, one n.
// GEMM K-dim slices = 8 channels x 2 taps; taps padded 9->10 (q=9 weights = 0,
// its B-read aliases q=8's address so no garbage/NaN enters the MFMA).
// A-frag: lane holds W[k=lane&31][c0+j] at q = 2p+(lane>>5)  (8 contiguous c -> b128)
// B-frag: lane holds x[c0+j][r_o+dy(q)][col+dx(q)] (channel-innermost LDS -> b128)
// D: col=lane&31, row k = 4*(lane>>5) + (reg&3) + 8*(reg>>2)   [measured m74/m101]
__global__ __launch_bounds__(256, 2) void sn_conv_mfma(
    const float* __restrict__ x, const unsigned short* __restrict__ wsp,
    const float* __restrict__ bias, float* __restrict__ out)
{
  __shared__ __align__(16) unsigned short wH[12800];  // [10 q][32 k][40 c-pad]
  __shared__ __align__(16) unsigned short wL[12800];
  __shared__ __align__(16) unsigned short sxH[5440];  // [10 r][68 col][8 c]
  __shared__ __align__(16) unsigned short sxL[5440];

  const int tid  = threadIdx.x;
  const int lane = tid & 63;
  const int wv   = tid >> 6;
  const int l31  = lane & 31;
  const int half = lane >> 5;
  const int n  = blockIdx.z;
  const int y0 = blockIdx.y * 8;
  const int x0 = blockIdx.x * 64;

  // zero weight LDS (q=9 dummy slice + padding must be exactly 0)
  {
    unsigned int* zH = (unsigned int*)wH;
    unsigned int* zL = (unsigned int*)wL;
    for (int i = tid; i < 6400; i += 256) { zH[i] = 0u; zL[i] = 0u; }
  }
  __syncthreads();  // zero must complete before cross-thread fills land
  for (int i = tid; i < 9216; i += 256) {
    int q = i >> 10, rem = i & 1023, k = rem >> 5, c = rem & 31;
    int d = (q * 32 + k) * 40 + c;
    wH[d] = wsp[i];
    wL[d] = wsp[9216 + i];
  }

  // bias folded into accumulator init; k = kb + (reg&3) + 8*(reg>>2)
  const int kb = 4 * half;
  const float4 b0 = *(const float4*)&bias[kb];
  const float4 b1 = *(const float4*)&bias[kb + 8];
  const float4 b2 = *(const float4*)&bias[kb + 16];
  const float4 b3 = *(const float4*)&bias[kb + 24];
  f32x16 acc0;
  acc0[0] = b0.x; acc0[1] = b0.y; acc0[2]  = b0.z; acc0[3]  = b0.w;
  acc0[4] = b1.x; acc0[5] = b1.y; acc0[6]  = b1.z; acc0[7]  = b1.w;
  acc0[8] = b2.x; acc0[9] = b2.y; acc0[10] = b2.z; acc0[11] = b2.w;
  acc0[12] = b3.x; acc0[13] = b3.y; acc0[14] = b3.z; acc0[15] = b3.w;
  f32x16 acc1 = acc0, acc2 = acc0, acc3 = acc0;

  // per-lane B offsets per K-slice p: q_b = min(2p+half, 8)
  int offB[5];
#pragma unroll
  for (int p = 0; p < 5; ++p) {
    int q = 2 * p + half; if (q > 8) q = 8;
    int dy = q / 3;
    int dx = q - 3 * dy;
    offB[p] = (dy * 68 + dx) * 8;
  }

  const float* xn = x + (size_t)n * 32 * 65536;

  for (int cs = 0; cs < 4; ++cs) {
    const int c0 = cs * 8;
    __syncthreads();  // previous iteration's B-reads done before overwrite
    // stage 8 channels + halo: fp32 -> bf16 hi/lo, layout [r][col][c] (c innermost)
    for (int idx = tid; idx < 660; idx += 256) {
      int r   = idx / 66;
      int col = idx - r * 66;
      int gy = y0 - 1 + r;
      int gx = x0 - 1 + col;
      bool ok = ((unsigned)gy < 256u) && ((unsigned)gx < 256u);
      const float* px = xn + (size_t)c0 * 65536 + gy * 256 + gx;
      u16x8 hv, lv;
#pragma unroll
      for (int cl = 0; cl < 8; ++cl) {
        float v = ok ? px[(size_t)cl * 65536] : 0.f;
        __bf16 hb = (__bf16)v;
        float rl = v - (float)hb;
        hv[cl] = __builtin_bit_cast(unsigned short, hb);
        lv[cl] = bf16bits(rl);
      }
      int d = (r * 68 + col) * 8;
      *(u16x8*)&sxH[d] = hv;
      *(u16x8*)&sxL[d] = lv;
    }
    __syncthreads();

    // A fragments for this channel slice (reused across 4 spatial tiles)
    frag8 aH[5], aL[5];
#pragma unroll
    for (int p = 0; p < 5; ++p) {
      int qa = 2 * p + half;  // 0..9; q=9 row is zeros
      int d = (qa * 32 + l31) * 40 + c0;
      aH[p] = __builtin_bit_cast(frag8, *(const u16x8*)&wH[d]);
      aL[p] = __builtin_bit_cast(frag8, *(const u16x8*)&wL[d]);
    }

#define LOAD_B(BH, BL, TT)                                                       \
    frag8 BH[5], BL[5];                                                          \
    {                                                                            \
      const int r_o = wv * 2 + ((TT) >> 1);                                      \
      const int dbase = (r_o * 68 + ((TT) & 1) * 32 + l31) * 8;                  \
      _Pragma("unroll")                                                          \
      for (int p = 0; p < 5; ++p) {                                              \
        BH[p] = __builtin_bit_cast(frag8, *(const u16x8*)&sxH[dbase + offB[p]]); \
        BL[p] = __builtin_bit_cast(frag8, *(const u16x8*)&sxL[dbase + offB[p]]); \
      }                                                                          \
    }

    {  // tiles 0,1 interleaved to break dependent-MFMA chains
      LOAD_B(bH0, bL0, 0)
      LOAD_B(bH1, bL1, 1)
#pragma unroll
      for (int p = 0; p < 5; ++p) {
        acc0 = __builtin_amdgcn_mfma_f32_32x32x16_bf16(aH[p], bH0[p], acc0, 0, 0, 0);
        acc1 = __builtin_amdgcn_mfma_f32_32x32x16_bf16(aH[p], bH1[p], acc1, 0, 0, 0);
        acc0 = __builtin_amdgcn_mfma_f32_32x32x16_bf16(aL[p], bH0[p], acc0, 0, 0, 0);
        acc1 = __builtin_amdgcn_mfma_f32_32x32x16_bf16(aL[p], bH1[p], acc1, 0, 0, 0);
        acc0 = __builtin_amdgcn_mfma_f32_32x32x16_bf16(aH[p], bL0[p], acc0, 0, 0, 0);
        acc1 = __builtin_amdgcn_mfma_f32_32x32x16_bf16(aH[p], bL1[p], acc1, 0, 0, 0);
      }
    }
    {  // tiles 2,3
      LOAD_B(bH2, bL2, 2)
      LOAD_B(bH3, bL3, 3)
#pragma unroll
      for (int p = 0; p < 5; ++p) {
        acc2 = __builtin_amdgcn_mfma_f32_32x32x16_bf16(aH[p], bH2[p], acc2, 0, 0, 0);
        acc3 = __builtin_amdgcn_mfma_f32_32x32x16_bf16(aH[p], bH3[p], acc3, 0, 0, 0);
        acc2 = __builtin_amdgcn_mfma_f32_32x32x16_bf16(aL[p], bH2[p], acc2, 0, 0, 0);
        acc3 = __builtin_amdgcn_mfma_f32_32x32x16_bf16(aL[p], bH3[p], acc3, 0, 0, 0);
        acc2 = __builtin_amdgcn_mfma_f32_32x32x16_bf16(aH[p], bL2[p], acc2, 0, 0, 0);
        acc3 = __builtin_amdgcn_mfma_f32_32x32x16_bf16(aH[p], bL3[p], acc3, 0, 0, 0);
      }
    }
#undef LOAD_B
  }

#define ST_TILE(ACC, TT)                                                        \
  {                                                                             \
    const int r_o = wv * 2 + ((TT) >> 1);                                       \
    const int gx = x0 + ((TT) & 1) * 32 + l31;                                  \
    float* op = out + ((size_t)n * 32 + kb) * 65536 + (y0 + r_o) * 256 + gx;    \
    _Pragma("unroll")                                                           \
    for (int reg = 0; reg < 16; ++reg) {                                        \
      int krel = (reg & 3) + 8 * (reg >> 2);                                    \
      op[(size_t)krel * 65536] = ACC[reg];                                      \
    }                                                                           \
  }

  ST_TILE(acc0, 0)
  ST_TILE(acc1, 1)
  ST_TILE(acc2, 2)
  ST_TILE(acc3, 3)
#undef ST_TILE
}

extern "C" void kernel_launch(void* const* d_in, const int* in_sizes, int n_in,
                              void* d_out, int out_size, void* d_ws, size_t ws_size,
                              hipStream_t stream) {
  (void)in_sizes; (void)n_in; (void)out_size; (void)ws_size;
  const float* x     = (const float*)d_in[0];
  const float* w_bar = (const float*)d_in[1];
  const float* bias  = (const float*)d_in[2];
  float* out = (float*)d_out;
  unsigned short* wS = (unsigned short*)d_ws;  // 2*9216 ushort = 36864 B scratch

  sn_prep_kernel<<<1, 256, 0, stream>>>(w_bar, wS);
  dim3 grid(256 / 64, 256 / 8, 32);   // (x-tiles, y-tiles, n)
  sn_conv_mfma<<<grid, 256, 0, stream>>>(x, wS, bias, out);
}

// Round 3
// 513.452 us; speedup vs baseline: 1.7744x; 1.0709x over previous
//
#include <hip/hip_runtime.h>
#include <math.h>

// SpectralNorm: sigma = max(1, s_max(w2d)/2); w = w_bar/sigma; conv3x3 pad1 + bias.
// x: [32,32,256,256] f32, w_bar: [32,32,3,3] f32, bias: [32] f32, out same as x.
//
// Conv = implicit GEMM on bf16 matrix cores, 3-term bf16 split
// (xhi*whi + xlo*whi + xhi*wlo) for fp32-equivalent accuracy.
// R3: 512-thr block, 16x64 tile -> LDS 78.25 KB -> 2 blocks/CU (16 waves, 50% occ)
//     vs R2's 8 waves/21%. Prep: 1024 threads + ILP unrolls.

typedef __attribute__((ext_vector_type(8))) __bf16 frag8;    // MFMA A/B operand (4 VGPR)
typedef __attribute__((ext_vector_type(16))) float f32x16;   // MFMA C/D (16 VGPR)
typedef __attribute__((ext_vector_type(8))) unsigned short u16x8;

__device__ __forceinline__ unsigned short bf16bits(float v) {
  __bf16 h = (__bf16)v;
  return __builtin_bit_cast(unsigned short, h);
}

// ---------------- prep: sigma via G = W W^T, squaring + power iter ----------------
// Output: bf16 hi/lo split of w_bar/sigma in [q][k][c] layout (q = 3*dy+dx).
__global__ __launch_bounds__(1024) void sn_prep_kernel(
    const float* __restrict__ w_bar,      // [32][288] row-major (k major)
    unsigned short* __restrict__ w_out)   // [2][9][32][32]: hi plane then lo plane
{
  __shared__ __align__(16) float sw[9216];    // [k][t]
  __shared__ __align__(16) float swT[9216];   // [t][k]
  __shared__ float G0[1024];
  __shared__ float Gpp[2048];
  __shared__ float vvec[32];
  __shared__ float svec[32];
  __shared__ float scal[2];
  const int tid = threadIdx.x;

  for (int i = tid; i < 9216; i += 1024) {
    float v = w_bar[i];
    sw[i] = v;
    int k = i / 288;
    int t = i - k * 288;
    swT[t * 32 + k] = v;
  }
  __syncthreads();

  // G[i][j] = dot(row i, row j) over 288; one element per thread, 2-chain ILP
  {
    const int i = tid >> 5, j = tid & 31;
    const float* ri = &sw[i * 288];
    float s0 = 0.f, s1 = 0.f;
    for (int t = 0; t < 288; t += 8) {
      float4 a = *(const float4*)(ri + t);
      float4 b = *(const float4*)(ri + t + 4);
      s0 = fmaf(a.x, swT[(t + 0) * 32 + j], s0);
      s0 = fmaf(a.y, swT[(t + 1) * 32 + j], s0);
      s0 = fmaf(a.z, swT[(t + 2) * 32 + j], s0);
      s0 = fmaf(a.w, swT[(t + 3) * 32 + j], s0);
      s1 = fmaf(b.x, swT[(t + 4) * 32 + j], s1);
      s1 = fmaf(b.y, swT[(t + 5) * 32 + j], s1);
      s1 = fmaf(b.z, swT[(t + 6) * 32 + j], s1);
      s1 = fmaf(b.w, swT[(t + 7) * 32 + j], s1);
    }
    G0[tid] = s0 + s1;
  }

  // 6 normalized squarings -> direction of G^64
  const float* src = G0;
  for (int sq = 0; sq < 6; ++sq) {
    float* dst = &Gpp[(sq & 1) * 1024];
    __syncthreads();
    {
      const int i = tid >> 5, j = tid & 31;
      float s0 = 0.f, s1 = 0.f;
#pragma unroll
      for (int t = 0; t < 32; t += 2) {
        s0 = fmaf(src[i * 32 + t], src[t * 32 + j], s0);
        s1 = fmaf(src[i * 32 + t + 1], src[(t + 1) * 32 + j], s1);
      }
      dst[tid] = s0 + s1;
    }
    __syncthreads();
    float s0 = dst[0];
    float inv = (s0 > 0.f) ? (1.f / s0) : 1.f;
    __syncthreads();
    dst[tid] *= inv;
    src = dst;
  }

  if (tid < 32) vvec[tid] = 1.f;
  __syncthreads();
  for (int it = 0; it < 4; ++it) {
    if (tid < 32) {
      float s = 0.f;
#pragma unroll
      for (int j = 0; j < 32; ++j) s = fmaf(src[tid * 32 + j], vvec[j], s);
      svec[tid] = s;
    }
    __syncthreads();
    if (tid == 0) {
      float n2 = 0.f;
      for (int j = 0; j < 32; ++j) n2 += svec[j] * svec[j];
      scal[0] = (n2 > 0.f) ? rsqrtf(n2) : 0.f;
    }
    __syncthreads();
    if (tid < 32) vvec[tid] = svec[tid] * scal[0];
    __syncthreads();
  }

  if (tid < 32) {
    float s = 0.f;
#pragma unroll
    for (int j = 0; j < 32; ++j) s = fmaf(G0[tid * 32 + j], vvec[j], s);
    svec[tid] = s * vvec[tid];
  }
  __syncthreads();
  if (tid == 0) {
    float lam = 0.f;
    for (int j = 0; j < 32; ++j) lam += svec[j];
    lam = fmaxf(lam, 0.f);
    float sigma = fmaxf(1.f, 0.5f * sqrtf(lam));
    scal[1] = 1.f / sigma;
  }
  __syncthreads();
  float inv_sigma = scal[1];
  // emit bf16 hi/lo in [q][k][c] layout (e = q*1024 + k*32 + c)
  for (int e = tid; e < 9216; e += 1024) {
    int q = e >> 10;
    int rem = e & 1023;
    int k = rem >> 5;
    int c = rem & 31;
    float w = sw[k * 288 + c * 9 + q] * inv_sigma;
    __bf16 hb = (__bf16)w;
    float lo = w - (float)hb;
    w_out[e] = __builtin_bit_cast(unsigned short, hb);
    w_out[9216 + e] = bf16bits(lo);
  }
}

// ---------------- conv: implicit GEMM on v_mfma_f32_32x32x16_bf16 ----------------
// Block: 512 thr (8 waves), tile = 16 out-rows x 64 cols x 32 k, one n.
// GEMM K-dim slices = 8 channels x 2 taps; taps padded 9->10 (q=9 weights = 0,
// its B-read aliases q=8's address so no garbage/NaN enters the MFMA).
// A-frag: lane holds W[k=lane&31][c0+j] at q = 2p+(lane>>5)  (8 contiguous c -> b128)
// B-frag: lane holds x[c0+j][r_o+dy(q)][col+dx(q)] (channel-innermost LDS -> b128)
// D: col=lane&31, row k = 4*(lane>>5) + (reg&3) + 8*(reg>>2)   [measured m74/m101]
__global__ __launch_bounds__(512, 4) void sn_conv_mfma(
    const float* __restrict__ x, const unsigned short* __restrict__ wsp,
    const float* __restrict__ bias, float* __restrict__ out)
{
  __shared__ __align__(16) unsigned short wH[10240];  // [10 q][32 k][32 c] (unpadded)
  __shared__ __align__(16) unsigned short wL[10240];
  __shared__ __align__(16) unsigned short sxH[9792];  // [18 r][68 col][8 c]
  __shared__ __align__(16) unsigned short sxL[9792];

  const int tid  = threadIdx.x;
  const int lane = tid & 63;
  const int wv   = tid >> 6;          // 0..7
  const int l31  = lane & 31;
  const int half = lane >> 5;
  const int n  = blockIdx.z;
  const int y0 = blockIdx.y * 16;
  const int x0 = blockIdx.x * 64;

  // weight fill (vectorized); q=9 dummy slice zeroed
  for (int i = tid; i < 1152; i += 512) {
    ((u16x8*)wH)[i] = ((const u16x8*)wsp)[i];
    ((u16x8*)wL)[i] = ((const u16x8*)(wsp + 9216))[i];
  }
  for (int i = tid; i < 1024; i += 512) {
    wH[9216 + i] = 0;
    wL[9216 + i] = 0;
  }

  // bias folded into accumulator init; k = kb + (reg&3) + 8*(reg>>2)
  const int kb = 4 * half;
  const float4 b0 = *(const float4*)&bias[kb];
  const float4 b1 = *(const float4*)&bias[kb + 8];
  const float4 b2 = *(const float4*)&bias[kb + 16];
  const float4 b3 = *(const float4*)&bias[kb + 24];
  f32x16 acc0;
  acc0[0] = b0.x; acc0[1] = b0.y; acc0[2]  = b0.z; acc0[3]  = b0.w;
  acc0[4] = b1.x; acc0[5] = b1.y; acc0[6]  = b1.z; acc0[7]  = b1.w;
  acc0[8] = b2.x; acc0[9] = b2.y; acc0[10] = b2.z; acc0[11] = b2.w;
  acc0[12] = b3.x; acc0[13] = b3.y; acc0[14] = b3.z; acc0[15] = b3.w;
  f32x16 acc1 = acc0, acc2 = acc0, acc3 = acc0;

  // per-lane B offsets per K-slice p: q_b = min(2p+half, 8)
  int offB[5];
#pragma unroll
  for (int p = 0; p < 5; ++p) {
    int q = 2 * p + half; if (q > 8) q = 8;
    int dy = q / 3;
    int dx = q - 3 * dy;
    offB[p] = (dy * 68 + dx) * 8;
  }

  const float* xn = x + (size_t)n * 32 * 65536;

  for (int cs = 0; cs < 4; ++cs) {
    const int c0 = cs * 8;
    __syncthreads();  // previous iteration's B-reads done before overwrite
    // stage 8 channels + halo: fp32 -> bf16 hi/lo, layout [r][col][c] (c innermost)
    for (int idx = tid; idx < 18 * 66; idx += 512) {
      int r   = idx / 66;
      int col = idx - r * 66;
      int gy = y0 - 1 + r;
      int gx = x0 - 1 + col;
      bool ok = ((unsigned)gy < 256u) && ((unsigned)gx < 256u);
      const float* px = xn + (size_t)c0 * 65536 + gy * 256 + gx;
      u16x8 hv, lv;
#pragma unroll
      for (int cl = 0; cl < 8; ++cl) {
        float v = ok ? px[(size_t)cl * 65536] : 0.f;
        __bf16 hb = (__bf16)v;
        float rl = v - (float)hb;
        hv[cl] = __builtin_bit_cast(unsigned short, hb);
        lv[cl] = bf16bits(rl);
      }
      int d = (r * 68 + col) * 8;
      *(u16x8*)&sxH[d] = hv;
      *(u16x8*)&sxL[d] = lv;
    }
    __syncthreads();

    // A fragments for this channel slice (reused across 4 spatial tiles)
    frag8 aH[5], aL[5];
#pragma unroll
    for (int p = 0; p < 5; ++p) {
      int qa = 2 * p + half;  // 0..9; q=9 row is zeros
      int d = qa * 1024 + l31 * 32 + c0;
      aH[p] = __builtin_bit_cast(frag8, *(const u16x8*)&wH[d]);
      aL[p] = __builtin_bit_cast(frag8, *(const u16x8*)&wL[d]);
    }

#define LOAD_B(BH, BL, TT)                                                       \
    frag8 BH[5], BL[5];                                                          \
    {                                                                            \
      const int r_o = wv * 2 + ((TT) >> 1);                                      \
      const int dbase = (r_o * 68 + ((TT) & 1) * 32 + l31) * 8;                  \
      _Pragma("unroll")                                                          \
      for (int p = 0; p < 5; ++p) {                                              \
        BH[p] = __builtin_bit_cast(frag8, *(const u16x8*)&sxH[dbase + offB[p]]); \
        BL[p] = __builtin_bit_cast(frag8, *(const u16x8*)&sxL[dbase + offB[p]]); \
      }                                                                          \
    }

    {  // tiles 0,1 interleaved to break dependent-MFMA chains
      LOAD_B(bH0, bL0, 0)
      LOAD_B(bH1, bL1, 1)
#pragma unroll
      for (int p = 0; p < 5; ++p) {
        acc0 = __builtin_amdgcn_mfma_f32_32x32x16_bf16(aH[p], bH0[p], acc0, 0, 0, 0);
        acc1 = __builtin_amdgcn_mfma_f32_32x32x16_bf16(aH[p], bH1[p], acc1, 0, 0, 0);
        acc0 = __builtin_amdgcn_mfma_f32_32x32x16_bf16(aL[p], bH0[p], acc0, 0, 0, 0);
        acc1 = __builtin_amdgcn_mfma_f32_32x32x16_bf16(aL[p], bH1[p], acc1, 0, 0, 0);
        acc0 = __builtin_amdgcn_mfma_f32_32x32x16_bf16(aH[p], bL0[p], acc0, 0, 0, 0);
        acc1 = __builtin_amdgcn_mfma_f32_32x32x16_bf16(aH[p], bL1[p], acc1, 0, 0, 0);
      }
    }
    {  // tiles 2,3
      LOAD_B(bH2, bL2, 2)
      LOAD_B(bH3, bL3, 3)
#pragma unroll
      for (int p = 0; p < 5; ++p) {
        acc2 = __builtin_amdgcn_mfma_f32_32x32x16_bf16(aH[p], bH2[p], acc2, 0, 0, 0);
        acc3 = __builtin_amdgcn_mfma_f32_32x32x16_bf16(aH[p], bH3[p], acc3, 0, 0, 0);
        acc2 = __builtin_amdgcn_mfma_f32_32x32x16_bf16(aL[p], bH2[p], acc2, 0, 0, 0);
        acc3 = __builtin_amdgcn_mfma_f32_32x32x16_bf16(aL[p], bH3[p], acc3, 0, 0, 0);
        acc2 = __builtin_amdgcn_mfma_f32_32x32x16_bf16(aH[p], bL2[p], acc2, 0, 0, 0);
        acc3 = __builtin_amdgcn_mfma_f32_32x32x16_bf16(aH[p], bL3[p], acc3, 0, 0, 0);
      }
    }
#undef LOAD_B
  }

#define ST_TILE(ACC, TT)                                                        \
  {                                                                             \
    const int r_o = wv * 2 + ((TT) >> 1);                                       \
    const int gx = x0 + ((TT) & 1) * 32 + l31;                                  \
    float* op = out + ((size_t)n * 32 + kb) * 65536 + (y0 + r_o) * 256 + gx;    \
    _Pragma("unroll")                                                           \
    for (int reg = 0; reg < 16; ++reg) {                                        \
      int krel = (reg & 3) + 8 * (reg >> 2);                                    \
      op[(size_t)krel * 65536] = ACC[reg];                                      \
    }                                                                           \
  }

  ST_TILE(acc0, 0)
  ST_TILE(acc1, 1)
  ST_TILE(acc2, 2)
  ST_TILE(acc3, 3)
#undef ST_TILE
}

extern "C" void kernel_launch(void* const* d_in, const int* in_sizes, int n_in,
                              void* d_out, int out_size, void* d_ws, size_t ws_size,
                              hipStream_t stream) {
  (void)in_sizes; (void)n_in; (void)out_size; (void)ws_size;
  const float* x     = (const float*)d_in[0];
  const float* w_bar = (const float*)d_in[1];
  const float* bias  = (const float*)d_in[2];
  float* out = (float*)d_out;
  unsigned short* wS = (unsigned short*)d_ws;  // 2*9216 ushort = 36864 B scratch

  sn_prep_kernel<<<1, 1024, 0, stream>>>(w_bar, wS);
  dim3 grid(256 / 64, 256 / 16, 32);  // (x-tiles, y-tiles, n)
  sn_conv_mfma<<<grid, 512, 0, stream>>>(x, wS, bias, out);
}